// Round 7
// baseline (534.263 us; speedup 1.0000x reference)
//
#include <hip/hip_runtime.h>
#include <math.h>

#define N_NODES 50000
#define N_EDGES 1600000
#define IN_DIM 128
#define N_HEADS 8
#define OUT_DIM 16
#define HD 128            // N_HEADS * OUT_DIM
#define NBUCK 784         // dst>>6: 64 nodes per bucket == one aggregate block
#define BCAP 2560         // region capacity per bucket (avg ~2041)
#define CHUNK 4096        // edges per bin block
#define BIN_BLOCKS ((N_EDGES + CHUNK - 1) / CHUNK)   // 391
#define NTILE 3125        // 50000/16 M-tiles (exact)
#define PBLK ((NTILE + 3) / 4)                        // 782 proj blocks (4 waves each)
#define TROW 132          // LDS tile row stride in floats (128 + 4 pad)
#define LOG2E 1.4426950408889634f
#define NPH 7             // src phases: phase = src >> 13 (8192 nodes = 2 MB ftb slice)
#define NB2 (NPH * NBUCK) // 5488 (phase, dst-bucket) cells
#define ANB 64            // nodes per aggregate block (== bucket size)
#define SENTU ((unsigned int)N_NODES)   // packed sentinel: nl=0, s=50000 (a1=-inf)

typedef __attribute__((ext_vector_type(8))) short bf16x8;
typedef __attribute__((ext_vector_type(4))) float f32x4;

__device__ __forceinline__ unsigned short f2bf(float f) {
    union { float f; unsigned int u; } v; v.f = f;
    unsigned int u = v.u;
    unsigned int r = (u + 0x7fffu + ((u >> 16) & 1u)) >> 16;   // RN-even
    return (unsigned short)r;
}

// exclusive scan of arr[0..NBUCK) in place; part[256] scratch; all 256 threads.
__device__ __forceinline__ void scan_nbuck_excl(int* arr, int* part) {
    int t = threadIdx.x;
    int v0 = 0, v1 = 0, v2 = 0, v3 = 0, cs = 0;
    if (t < NBUCK / 4) {
        v0 = arr[4 * t]; v1 = arr[4 * t + 1]; v2 = arr[4 * t + 2]; v3 = arr[4 * t + 3];
        cs = v0 + v1 + v2 + v3;
    }
    part[t] = cs;
    __syncthreads();
    for (int d = 1; d < 256; d <<= 1) {
        int u = (t >= d) ? part[t - d] : 0;
        __syncthreads();
        part[t] += u;
        __syncthreads();
    }
    if (t < NBUCK / 4) {
        int run = part[t] - cs;
        arr[4 * t] = run; run += v0;
        arr[4 * t + 1] = run; run += v1;
        arr[4 * t + 2] = run; run += v2;
        arr[4 * t + 3] = run;
    }
    __syncthreads();
}

// exclusive scan over arr[0..n) in place (n <= 256*K any), part[256] scratch.
__device__ __forceinline__ void scan_flat_excl(int* arr, int n, int* part) {
    int t = threadIdx.x;
    int K = (n + 255) / 256;
    int base = t * K;
    int cs = 0;
    for (int k = 0; k < K; k++) { int idx = base + k; if (idx < n) cs += arr[idx]; }
    part[t] = cs;
    __syncthreads();
    for (int d = 1; d < 256; d <<= 1) {
        int u = (t >= d) ? part[t - d] : 0;
        __syncthreads();
        part[t] += u;
        __syncthreads();
    }
    int run = part[t] - cs;
    for (int k = 0; k < K; k++) {
        int idx = base + k;
        if (idx < n) { int v = arr[idx]; arr[idx] = run; run += v; }
    }
    __syncthreads();
}

// ---------------- prep: W(f32) -> Wb(bf16) + zero counters + sentinel rows ----
// Sentinel node N_NODES: a1 row = -inf (exp2 -> 0 => free edge masking in
// aggregate), ftb row = 0 (so e=0 times finite 0 => no NaN).
__global__ void k_prep(const float* __restrict__ W, unsigned short* __restrict__ Wb,
                       int* __restrict__ bucket_cnt, int* __restrict__ cntp,
                       int* __restrict__ ovf_cnt,
                       unsigned short* __restrict__ ftb, float* __restrict__ a1) {
    int g = blockIdx.x * 256 + threadIdx.x;   // 32 blocks -> 8192 threads
    if (g < NBUCK) bucket_cnt[g] = 0;
    if (g < NB2) cntp[g] = 0;
    if (g == 0) *ovf_cnt = 0;
    if (g < 64) ((unsigned int*)(ftb + (size_t)N_NODES * HD))[g] = 0u;
    if (g >= 64 && g < 64 + N_HEADS)
        a1[(size_t)N_NODES * N_HEADS + (g - 64)] = __int_as_float(0xff800000); // -inf
    if (g >= (HD * IN_DIM) / 4) return;
    float4 v = ((const float4*)W)[g];
    ushort4 us;
    us.x = f2bf(v.x); us.y = f2bf(v.y); us.z = f2bf(v.z); us.w = f2bf(v.w);
    ((ushort4*)Wb)[g] = us;
}

// ---------------- fused: MFMA projection (blocks < PBLK) | edge binning ----------
__global__ __launch_bounds__(256) void k_proj_bin(
    const float* __restrict__ x, const unsigned short* __restrict__ Wb,
    const float* __restrict__ attn_l, const float* __restrict__ attn_r,
    unsigned short* __restrict__ ftb, float* __restrict__ a1, float* __restrict__ a2,
    const int* __restrict__ src, const int* __restrict__ dst,
    unsigned int* __restrict__ region, int* __restrict__ bucket_cnt,
    int* __restrict__ cntp, int* __restrict__ ovf_cnt, unsigned int* __restrict__ ovf) {
    // union: proj 4 wave-private f32 tiles 16x132 (33792 B) | bin 23680 B
    __shared__ __align__(16) char smem[4 * 16 * TROW * 4];
    int tid = threadIdx.x;

    if (blockIdx.x < PBLK) {
        // ---------------- MFMA projection branch ----------------
        int wid  = tid >> 6;
        int tile = blockIdx.x * 4 + wid;
        if (tile >= NTILE) return;           // no barriers in this branch
        int lane = tid & 63;
        int m = lane & 15, q = lane >> 4;
        int node0 = tile * 16;

        // A fragments: x[node0+m][ks*32 + q*8 .. +7], fp32 -> bf16
        const float* xr = x + (size_t)(node0 + m) * IN_DIM + q * 8;
        float4 xa[4][2];
#pragma unroll
        for (int ks = 0; ks < 4; ks++) {
            xa[ks][0] = *(const float4*)(xr + ks * 32);
            xa[ks][1] = *(const float4*)(xr + ks * 32 + 4);
        }
        bf16x8 afr[4];
#pragma unroll
        for (int ks = 0; ks < 4; ks++) {
            afr[ks][0] = (short)f2bf(xa[ks][0].x); afr[ks][1] = (short)f2bf(xa[ks][0].y);
            afr[ks][2] = (short)f2bf(xa[ks][0].z); afr[ks][3] = (short)f2bf(xa[ks][0].w);
            afr[ks][4] = (short)f2bf(xa[ks][1].x); afr[ks][5] = (short)f2bf(xa[ks][1].y);
            afr[ks][6] = (short)f2bf(xa[ks][1].z); afr[ks][7] = (short)f2bf(xa[ks][1].w);
        }

        float* tl = (float*)smem + wid * (16 * TROW);

        // heads loop: B frag = Wb[h*16+m][ks*32 + q*8 .. +7] (original W layout!)
#pragma unroll
        for (int h = 0; h < N_HEADS; h++) {
            const unsigned short* wrow = Wb + (size_t)(h * 16 + m) * IN_DIM + q * 8;
            f32x4 c = {0.f, 0.f, 0.f, 0.f};
#pragma unroll
            for (int ks = 0; ks < 4; ks++) {
                bf16x8 bfr = *(const bf16x8*)(wrow + ks * 32);
                c = __builtin_amdgcn_mfma_f32_16x16x32_bf16(afr[ks], bfr, c, 0, 0, 0);
            }
            // C layout: col = lane&15, row = q*4 + reg  -> stash in LDS tile
#pragma unroll
            for (int r = 0; r < 4; r++)
                tl[(q * 4 + r) * TROW + h * 16 + m] = c[r];
        }

        // a1/a2: lane -> node (lane&15), heads {lane>>4, (lane>>4)+4}
        // NOTE: pre-scaled by log2(e) so aggregate can use raw v_exp_f32 (2^x).
        int nd = lane & 15;
#pragma unroll
        for (int hi = 0; hi < 2; hi++) {
            int hh = (lane >> 4) + hi * 4;
            const float4* rowv = (const float4*)(tl + nd * TROW + hh * 16);
            const float4* alv  = (const float4*)(attn_l + hh * OUT_DIM);
            const float4* arv  = (const float4*)(attn_r + hh * OUT_DIM);
            float sl = 0.f, sr = 0.f;
#pragma unroll
            for (int d4 = 0; d4 < 4; d4++) {
                float4 fv = rowv[d4];
                float4 al = alv[d4];
                float4 ar = arv[d4];
                sl += fv.x * al.x + fv.y * al.y + fv.z * al.z + fv.w * al.w;
                sr += fv.x * ar.x + fv.y * ar.y + fv.z * ar.z + fv.w * ar.w;
            }
            a1[(node0 + nd) * N_HEADS + hh] = sl * LOG2E;
            a2[(node0 + nd) * N_HEADS + hh] = sr * LOG2E;
        }

        // ft store: pass p covers rows p*4+q; lane m covers 8 cols
#pragma unroll
        for (int p = 0; p < 4; p++) {
            int r = p * 4 + q;
            const float* srcp = tl + r * TROW + m * 8;
            float4 f0 = *(const float4*)(srcp);
            float4 f1 = *(const float4*)(srcp + 4);
            ushort4 u0, u1;
            u0.x = f2bf(f0.x); u0.y = f2bf(f0.y); u0.z = f2bf(f0.z); u0.w = f2bf(f0.w);
            u1.x = f2bf(f1.x); u1.y = f2bf(f1.y); u1.z = f2bf(f1.z); u1.w = f2bf(f1.w);
            ushort4* dstp = (ushort4*)(ftb + (size_t)(node0 + r) * HD + m * 8);
            dstp[0] = u0;
            dstp[1] = u1;
        }
    } else {
        // ---------------- binning branch ----------------
        unsigned int* stage = (unsigned int*)smem;          // 16 KB
        int* hist  = (int*)(smem + 16384);                  // NBUCK
        int* delta = (int*)(smem + 19520);                  // NBUCK
        int* part  = (int*)(smem + 22656);                  // 256

        int t = tid;
        int base = (blockIdx.x - PBLK) * CHUNK;
        int nvalid = min(CHUNK, N_EDGES - base);

        for (int i = t; i < NBUCK; i += 256) hist[i] = 0;
        __syncthreads();

        unsigned int mypack[CHUNK / 256];
#pragma unroll
        for (int k = 0; k < CHUNK / 256; k++) {
            int i = t + k * 256;
            if (i < nvalid) {
                int s = src[base + i];
                int d = dst[base + i];
                unsigned int p = ((unsigned int)d << 16) | (unsigned int)s;
                mypack[k] = p;
                atomicAdd(&hist[d >> 6], 1);
                atomicAdd(&cntp[(s >> 13) * NBUCK + (d >> 6)], 1);  // (phase,bucket) totals
            }
        }
        __syncthreads();
        for (int i = t; i < NBUCK; i += 256) {
            int h = hist[i];
            delta[i] = (h > 0) ? atomicAdd(&bucket_cnt[i], h) : 0;
        }
        __syncthreads();
        scan_nbuck_excl(hist, part);            // hist -> local exclusive offsets
        for (int i = t; i < NBUCK; i += 256) delta[i] -= hist[i];
        __syncthreads();
#pragma unroll
        for (int k = 0; k < CHUNK / 256; k++) {
            int i = t + k * 256;
            if (i < nvalid) {
                unsigned int p = mypack[k];
                int slot = atomicAdd(&hist[p >> 22], 1);
                stage[slot] = p;
            }
        }
        __syncthreads();
        for (int i = t; i < nvalid; i += 256) {
            unsigned int p = stage[i];
            int b = p >> 22;
            int pos = delta[b] + i;
            if (pos < BCAP) region[(size_t)b * BCAP + pos] = p;
            else { int o = atomicAdd(ovf_cnt, 1); ovf[o] = p; }
        }
    }
}

// ---------------- k_place v8: phase-major placement, u32 stream -----------------
// esrc32 sorted by (phase, dst): entry = (dst_local6 << 16) | src16. Emits only
// per-(phase,bucket) range bounds pstart/pend (bucket == aggregate block).
__global__ __launch_bounds__(256) void k_place(
    const unsigned int* __restrict__ region, const int* __restrict__ bucket_cnt,
    const int* __restrict__ cntp, const int* __restrict__ ovf_cnt,
    const unsigned int* __restrict__ ovf,
    int* __restrict__ pstart, int* __restrict__ pend,
    unsigned int* __restrict__ esrc32) {
    int b = blockIdx.x;
    int t = threadIdx.x;
    __shared__ int cpb[NB2], part[256];
    __shared__ int hist[NPH * 64];      // (phase-major, node-minor) counts -> offsets
    __shared__ int curs[NPH * 64];
    __shared__ int gstart[NPH], lstart[NPH], phtot[NPH];
    __shared__ unsigned int sstage[BCAP];

    for (int i = t; i < NB2; i += 256) cpb[i] = cntp[i];
    for (int i = t; i < NPH * 64; i += 256) hist[i] = 0;
    __syncthreads();
    scan_flat_excl(cpb, NB2, part);     // global phase-major exclusive positions

    int truec = bucket_cnt[b];
    int rc = min(truec, BCAP);
    bool fits = (truec <= BCAP);        // statistically always true
    const unsigned int* reg = region + (size_t)b * BCAP;

    for (int i = t; i < rc; i += 256) {
        unsigned int pk = reg[i];
        int key = (int)((pk & 0xffffu) >> 13) * 64 + (int)((pk >> 16) & 63);
        atomicAdd(&hist[key], 1);
    }
    int no = 0;
    if (truec > BCAP) {                 // correctness fallback
        no = *ovf_cnt;
        for (int i = t; i < no; i += 256)
            if ((int)(ovf[i] >> 22) == b) {
                unsigned int pk = ovf[i];
                int key = (int)((pk & 0xffffu) >> 13) * 64 + (int)((pk >> 16) & 63);
                atomicAdd(&hist[key], 1);
            }
    }
    __syncthreads();
    scan_flat_excl(hist, NPH * 64, part);   // local phase-major layout offsets

    if (t < NPH) {
        gstart[t] = cpb[t * NBUCK + b];
        lstart[t] = hist[t * 64];
        phtot[t]  = ((t == NPH - 1) ? truec : hist[(t + 1) * 64]) - hist[t * 64];
    }
    __syncthreads();

    if (t < NPH) {
        pstart[t * NBUCK + b] = gstart[t];
        pend[t * NBUCK + b]   = gstart[t] + phtot[t];
    }
    for (int i = t; i < NPH * 64; i += 256) {
        int p = i >> 6;
        curs[i] = fits ? hist[i] : (gstart[p] + hist[i] - lstart[p]);
    }
    __syncthreads();

    for (int i = t; i < rc; i += 256) {
        unsigned int pk = reg[i];
        int key = (int)((pk & 0xffffu) >> 13) * 64 + (int)((pk >> 16) & 63);
        int pos = atomicAdd(&curs[key], 1);
        unsigned int ent = (((pk >> 16) & 63u) << 16) | (pk & 0xffffu);
        if (fits) sstage[pos] = ent;
        else      esrc32[pos] = ent;
    }
    if (truec > BCAP) {
        for (int i = t; i < no; i += 256) {
            unsigned int pk = ovf[i];
            if ((int)(pk >> 22) == b) {
                int key = (int)((pk & 0xffffu) >> 13) * 64 + (int)((pk >> 16) & 63);
                int pos = atomicAdd(&curs[key], 1);
                esrc32[pos] = (((pk >> 16) & 63u) << 16) | (pk & 0xffffu);
            }
        }
    }
    __syncthreads();
    if (fits) {
        for (int p = 0; p < NPH; p++)
            for (int i = t; i < phtot[p]; i += 256)
                esrc32[gstart[p] + i] = sstage[lstart[p] + i];   // coalesced copy-out
    }
}

// ---------------- aggregation v8: phase-blocked + LDS accumulators --------------
// Block == bucket (64 nodes); facc[64][128] + ldenom[64][8] live in LDS, so the
// node-boundary "which accumulator" problem becomes a dynamically-computed LDS
// address (free) instead of v7's register-select machinery (fatal). Per-slot
// work is R2's proven pipeline + one scalar compare; on node-change (wave-
// uniform branch, ~1/5 slots) flush (tx,ty,tl) via 3 LDS atomics and reload
// cura2 from the block's a2 slice. 784 blocks all co-resident (36 KB LDS, 4
// blocks/CU) -> true phase coherence: all blocks sweep src-phase p together,
// keeping the 2 MB ftb slice + 256 KB a1 slice L2-resident.
template <int KK>
__device__ __forceinline__ void issue16(unsigned int uv, const float* __restrict__ a1,
                                        const unsigned short* __restrict__ ftb,
                                        int hl, int dimoff,
                                        float* a1v, unsigned int* pv) {
#pragma unroll
    for (int j = 0; j < 16; j++) {
        unsigned int u = __builtin_amdgcn_readlane(uv, KK + j);   // SGPR
        int s = (int)(u & 0xffffu);
        a1v[j] = a1[(size_t)s * N_HEADS + hl];
        pv[j]  = *(const unsigned int*)(ftb + (size_t)s * HD + dimoff);
    }
}

#define FLUSHLDS()                                                          \
    {                                                                       \
        atomicAdd(&facc[cur * HD + dimoff], tx);                            \
        atomicAdd(&facc[cur * HD + dimoff + 1], ty);                        \
        if ((lane & 7) == 0) atomicAdd(&ldenom[cur * N_HEADS + hl], tl);    \
    }

#define CONS16(AV, PV, KK)                                                  \
    {                                                                       \
        _Pragma("unroll")                                                   \
        for (int j = 0; j < 16; j++) {                                      \
            unsigned int u = __builtin_amdgcn_readlane(uv, (KK) + j);       \
            int nl = (int)(u >> 16);                                        \
            if (nl != cur) {                                                \
                if (cur >= 0) FLUSHLDS();                                   \
                tx = ty = tl = 0.f;                                         \
                cur = nl;                                                   \
                cura2 = a2sl[nl * N_HEADS + hl];                            \
            }                                                               \
            float tt = AV[j] + cura2;                                       \
            float uu = fmaxf(tt, 0.2f * tt);                                \
            float ee;                                                       \
            asm("v_exp_f32 %0, %1" : "=v"(ee) : "v"(uu));                   \
            tl += ee;                                                       \
            tx = fmaf(ee, __uint_as_float(PV[j] << 16), tx);                \
            ty = fmaf(ee, __uint_as_float(PV[j] & 0xffff0000u), ty);        \
        }                                                                   \
    }

__global__ __launch_bounds__(256, 4) void k_aggregate(
    const unsigned short* __restrict__ ftb, const float* __restrict__ a1,
    const float* __restrict__ a2, const int* __restrict__ pstart,
    const int* __restrict__ pend, const unsigned int* __restrict__ esrc32,
    float* __restrict__ out) {
    int b = blockIdx.x;
    int t = threadIdx.x;
    int wid = t >> 6, lane = t & 63;
    int hl = lane >> 3;
    int dimoff = lane * 2;

    __shared__ __align__(16) float facc[ANB * HD];     // 32 KB
    __shared__ float ldenom[ANB * N_HEADS];            // 2 KB
    __shared__ float a2sl[ANB * N_HEADS];              // 2 KB

    for (int i = t; i < ANB * HD; i += 256) facc[i] = 0.f;
    for (int i = t; i < ANB * N_HEADS; i += 256) {
        ldenom[i] = 0.f;
        int node = b * ANB + (i >> 3);
        a2sl[i] = (node < N_NODES) ? a2[(size_t)node * N_HEADS + (i & 7)] : 0.f;
    }
    __syncthreads();

    for (int p = 0; p < NPH; p++) {
        int pb = __builtin_amdgcn_readfirstlane(pstart[p * NBUCK + b]);
        int pe = __builtin_amdgcn_readfirstlane(pend[p * NBUCK + b]);
        int nch = (pe - pb + 63) >> 6;
        for (int c = wid; c < nch; c += 4) {
            int cb = pb + (c << 6);
            int nbc = pe - cb; if (nbc > 64) nbc = 64;
            unsigned int ecv = esrc32[cb + lane];       // coalesced; pad covers tail
            unsigned int uv = (lane < nbc) ? ecv : SENTU;

            float a1A[16], a1B[16];
            unsigned int pA[16], pB[16];
            int cur = -1;
            float tx = 0.f, ty = 0.f, tl = 0.f, cura2 = 0.f;

            issue16<0>(uv, a1, ftb, hl, dimoff, a1A, pA);
            if (nbc > 16) issue16<16>(uv, a1, ftb, hl, dimoff, a1B, pB);
            CONS16(a1A, pA, 0);
            if (nbc > 32) issue16<32>(uv, a1, ftb, hl, dimoff, a1A, pA);
            if (nbc > 16) CONS16(a1B, pB, 16);
            if (nbc > 48) issue16<48>(uv, a1, ftb, hl, dimoff, a1B, pB);
            if (nbc > 32) CONS16(a1A, pA, 32);
            if (nbc > 48) CONS16(a1B, pB, 48);
            if (cur >= 0) FLUSHLDS();
        }
    }
    __syncthreads();

    // epilogue: out[node][dim] = facc / ldenom, coalesced float4
    int vn = N_NODES - b * ANB; if (vn > ANB) vn = ANB;
    for (int i = t; i < ANB * (HD / 4); i += 256) {      // 2048 float4
        int n = i >> 5, d4 = i & 31;
        if (n < vn) {
            float4 v = *(const float4*)&facc[n * HD + d4 * 4];
            float ls = ldenom[n * N_HEADS + (d4 >> 2)];
            float inv = (ls > 0.f) ? 1.f / ls : 0.f;
            v.x *= inv; v.y *= inv; v.z *= inv; v.w *= inv;
            *(float4*)&out[(size_t)(b * ANB + n) * HD + d4 * 4] = v;
        }
    }
}

// ---------------- host launcher ----------------
extern "C" void kernel_launch(void* const* d_in, const int* in_sizes, int n_in,
                              void* d_out, int out_size, void* d_ws, size_t ws_size,
                              hipStream_t stream) {
    const float* x      = (const float*)d_in[0];
    const float* W      = (const float*)d_in[1];
    const float* attn_l = (const float*)d_in[2];
    const float* attn_r = (const float*)d_in[3];
    const int*   src    = (const int*)d_in[4];
    const int*   dst    = (const int*)d_in[5];
    float* out = (float*)d_out;

    char* ws = (char*)d_ws;
    size_t o = 0;
    auto alloc = [&](size_t bytes) -> char* {
        char* p = ws + o;
        o = (o + bytes + 255) & ~(size_t)255;
        return p;
    };
    // +1 sentinel row on ftb (zeros) and a1 (-inf)
    unsigned short* ftb  = (unsigned short*)alloc((size_t)(N_NODES + 1) * HD * 2);
    float* a1            = (float*)alloc((size_t)(N_NODES + 1) * N_HEADS * 4);
    float* a2            = (float*)alloc((size_t)N_NODES * N_HEADS * 4);
    unsigned short* Wb   = (unsigned short*)alloc((size_t)HD * IN_DIM * 2);    // 32 KB
    unsigned int* region = (unsigned int*)alloc((size_t)NBUCK * BCAP * 4);     // 8.0 MB
    int* bucket_cnt      = (int*)alloc((size_t)NBUCK * 4);
    int* cntp            = (int*)alloc((size_t)NB2 * 4);                       // 22 KB
    int* ovf_cnt         = (int*)alloc(4);
    unsigned int* ovf    = (unsigned int*)alloc((size_t)N_EDGES * 4);          // 6.4 MB
    int* pstart          = (int*)alloc((size_t)NB2 * 4);                       // 22 KB
    int* pend            = (int*)alloc((size_t)NB2 * 4);                       // 22 KB
    unsigned int* esrc32 = (unsigned int*)alloc((size_t)N_EDGES * 4 + 256);    // 6.4 MB +pad

    (void)in_sizes; (void)n_in; (void)out_size; (void)ws_size;

    k_prep<<<32, 256, 0, stream>>>(W, Wb, bucket_cnt, cntp, ovf_cnt, ftb, a1);
    k_proj_bin<<<PBLK + BIN_BLOCKS, 256, 0, stream>>>(
        x, Wb, attn_l, attn_r, ftb, a1, a2,
        src, dst, region, bucket_cnt, cntp, ovf_cnt, ovf);
    k_place<<<NBUCK, 256, 0, stream>>>(region, bucket_cnt, cntp, ovf_cnt, ovf,
                                       pstart, pend, esrc32);
    k_aggregate<<<NBUCK, 256, 0, stream>>>(ftb, a1, a2, pstart, pend, esrc32, out);
}

// Round 8
// 211.624 us; speedup vs baseline: 2.5246x; 2.5246x over previous
//
#include <hip/hip_runtime.h>
#include <math.h>

#define N_NODES 50000
#define N_EDGES 1600000
#define IN_DIM 128
#define N_HEADS 8
#define OUT_DIM 16
#define HD 128            // N_HEADS * OUT_DIM
#define NBUCK 784         // dst>>6: 64 nodes per bucket == one place_agg block
#define BCAP 2560         // region capacity per bucket (avg ~2041, sigma ~45)
#define CHUNK 4096        // edges per bin block
#define BIN_BLOCKS ((N_EDGES + CHUNK - 1) / CHUNK)   // 391
#define NTILE 3125        // 50000/16 M-tiles (exact)
#define PBLK ((NTILE + 3) / 4)                        // 782 proj blocks (4 waves each)
#define TROW 132          // LDS tile row stride in floats (128 + 4 pad)
#define LOG2E 1.4426950408889634f

typedef __attribute__((ext_vector_type(8))) short bf16x8;
typedef __attribute__((ext_vector_type(4))) float f32x4;

__device__ __forceinline__ unsigned short f2bf(float f) {
    union { float f; unsigned int u; } v; v.f = f;
    unsigned int u = v.u;
    unsigned int r = (u + 0x7fffu + ((u >> 16) & 1u)) >> 16;   // RN-even
    return (unsigned short)r;
}

// exclusive scan of arr[0..NBUCK) in place; part[256] scratch; all 256 threads.
__device__ __forceinline__ void scan_nbuck_excl(int* arr, int* part) {
    int t = threadIdx.x;
    int v0 = 0, v1 = 0, v2 = 0, v3 = 0, cs = 0;
    if (t < NBUCK / 4) {
        v0 = arr[4 * t]; v1 = arr[4 * t + 1]; v2 = arr[4 * t + 2]; v3 = arr[4 * t + 3];
        cs = v0 + v1 + v2 + v3;
    }
    part[t] = cs;
    __syncthreads();
    for (int d = 1; d < 256; d <<= 1) {
        int u = (t >= d) ? part[t - d] : 0;
        __syncthreads();
        part[t] += u;
        __syncthreads();
    }
    if (t < NBUCK / 4) {
        int run = part[t] - cs;
        arr[4 * t] = run; run += v0;
        arr[4 * t + 1] = run; run += v1;
        arr[4 * t + 2] = run; run += v2;
        arr[4 * t + 3] = run;
    }
    __syncthreads();
}

// ---------------- prep: W(f32) -> Wb(bf16) + zero counters + sentinel rows ----
// Sentinel node N_NODES: a1 row = -inf (exp2 -> 0 => free edge masking in
// aggregate), ftb row = 0 (so e=0 times finite 0 => no NaN).
__global__ void k_prep(const float* __restrict__ W, unsigned short* __restrict__ Wb,
                       int* __restrict__ bucket_cnt, int* __restrict__ ovf_cnt,
                       unsigned short* __restrict__ ftb, float* __restrict__ a1) {
    int g = blockIdx.x * 256 + threadIdx.x;   // 4096 threads over 4096 float4s
    if (g < NBUCK) bucket_cnt[g] = 0;
    if (g == 0) *ovf_cnt = 0;
    if (g < 64) ((unsigned int*)(ftb + (size_t)N_NODES * HD))[g] = 0u;
    if (g >= 64 && g < 64 + N_HEADS)
        a1[(size_t)N_NODES * N_HEADS + (g - 64)] = __int_as_float(0xff800000); // -inf
    if (g >= (HD * IN_DIM) / 4) return;
    float4 v = ((const float4*)W)[g];
    ushort4 us;
    us.x = f2bf(v.x); us.y = f2bf(v.y); us.z = f2bf(v.z); us.w = f2bf(v.w);
    ((ushort4*)Wb)[g] = us;
}

// ---------------- fused: MFMA projection (blocks < PBLK) | edge binning ----------
__global__ __launch_bounds__(256) void k_proj_bin(
    const float* __restrict__ x, const unsigned short* __restrict__ Wb,
    const float* __restrict__ attn_l, const float* __restrict__ attn_r,
    unsigned short* __restrict__ ftb, float* __restrict__ a1, float* __restrict__ a2,
    const int* __restrict__ src, const int* __restrict__ dst,
    unsigned int* __restrict__ region, int* __restrict__ bucket_cnt,
    int* __restrict__ ovf_cnt, unsigned int* __restrict__ ovf) {
    // union: proj 4 wave-private f32 tiles 16x132 (33792 B) | bin 23680 B
    __shared__ __align__(16) char smem[4 * 16 * TROW * 4];
    int tid = threadIdx.x;

    if (blockIdx.x < PBLK) {
        // ---------------- MFMA projection branch ----------------
        int wid  = tid >> 6;
        int tile = blockIdx.x * 4 + wid;
        if (tile >= NTILE) return;           // no barriers in this branch
        int lane = tid & 63;
        int m = lane & 15, q = lane >> 4;
        int node0 = tile * 16;

        // A fragments: x[node0+m][ks*32 + q*8 .. +7], fp32 -> bf16
        const float* xr = x + (size_t)(node0 + m) * IN_DIM + q * 8;
        float4 xa[4][2];
#pragma unroll
        for (int ks = 0; ks < 4; ks++) {
            xa[ks][0] = *(const float4*)(xr + ks * 32);
            xa[ks][1] = *(const float4*)(xr + ks * 32 + 4);
        }
        bf16x8 afr[4];
#pragma unroll
        for (int ks = 0; ks < 4; ks++) {
            afr[ks][0] = (short)f2bf(xa[ks][0].x); afr[ks][1] = (short)f2bf(xa[ks][0].y);
            afr[ks][2] = (short)f2bf(xa[ks][0].z); afr[ks][3] = (short)f2bf(xa[ks][0].w);
            afr[ks][4] = (short)f2bf(xa[ks][1].x); afr[ks][5] = (short)f2bf(xa[ks][1].y);
            afr[ks][6] = (short)f2bf(xa[ks][1].z); afr[ks][7] = (short)f2bf(xa[ks][1].w);
        }

        float* tl = (float*)smem + wid * (16 * TROW);

        // heads loop: B frag = Wb[h*16+m][ks*32 + q*8 .. +7] (original W layout!)
#pragma unroll
        for (int h = 0; h < N_HEADS; h++) {
            const unsigned short* wrow = Wb + (size_t)(h * 16 + m) * IN_DIM + q * 8;
            f32x4 c = {0.f, 0.f, 0.f, 0.f};
#pragma unroll
            for (int ks = 0; ks < 4; ks++) {
                bf16x8 bfr = *(const bf16x8*)(wrow + ks * 32);
                c = __builtin_amdgcn_mfma_f32_16x16x32_bf16(afr[ks], bfr, c, 0, 0, 0);
            }
            // C layout: col = lane&15, row = q*4 + reg  -> stash in LDS tile
#pragma unroll
            for (int r = 0; r < 4; r++)
                tl[(q * 4 + r) * TROW + h * 16 + m] = c[r];
        }

        // a1/a2: lane -> node (lane&15), heads {lane>>4, (lane>>4)+4}
        // NOTE: pre-scaled by log2(e) so aggregate can use raw v_exp_f32 (2^x).
        int nd = lane & 15;
#pragma unroll
        for (int hi = 0; hi < 2; hi++) {
            int hh = (lane >> 4) + hi * 4;
            const float4* rowv = (const float4*)(tl + nd * TROW + hh * 16);
            const float4* alv  = (const float4*)(attn_l + hh * OUT_DIM);
            const float4* arv  = (const float4*)(attn_r + hh * OUT_DIM);
            float sl = 0.f, sr = 0.f;
#pragma unroll
            for (int d4 = 0; d4 < 4; d4++) {
                float4 fv = rowv[d4];
                float4 al = alv[d4];
                float4 ar = arv[d4];
                sl += fv.x * al.x + fv.y * al.y + fv.z * al.z + fv.w * al.w;
                sr += fv.x * ar.x + fv.y * ar.y + fv.z * ar.z + fv.w * ar.w;
            }
            a1[(node0 + nd) * N_HEADS + hh] = sl * LOG2E;
            a2[(node0 + nd) * N_HEADS + hh] = sr * LOG2E;
        }

        // ft store: pass p covers rows p*4+q; lane m covers 8 cols
#pragma unroll
        for (int p = 0; p < 4; p++) {
            int r = p * 4 + q;
            const float* srcp = tl + r * TROW + m * 8;
            float4 f0 = *(const float4*)(srcp);
            float4 f1 = *(const float4*)(srcp + 4);
            ushort4 u0, u1;
            u0.x = f2bf(f0.x); u0.y = f2bf(f0.y); u0.z = f2bf(f0.z); u0.w = f2bf(f0.w);
            u1.x = f2bf(f1.x); u1.y = f2bf(f1.y); u1.z = f2bf(f1.z); u1.w = f2bf(f1.w);
            ushort4* dstp = (ushort4*)(ftb + (size_t)(node0 + r) * HD + m * 8);
            dstp[0] = u0;
            dstp[1] = u1;
        }
    } else {
        // ---------------- binning branch ----------------
        unsigned int* stage = (unsigned int*)smem;          // 16 KB
        int* hist  = (int*)(smem + 16384);                  // NBUCK
        int* delta = (int*)(smem + 19520);                  // NBUCK
        int* part  = (int*)(smem + 22656);                  // 256

        int t = tid;
        int base = (blockIdx.x - PBLK) * CHUNK;
        int nvalid = min(CHUNK, N_EDGES - base);

        for (int i = t; i < NBUCK; i += 256) hist[i] = 0;
        __syncthreads();

        unsigned int mypack[CHUNK / 256];
#pragma unroll
        for (int k = 0; k < CHUNK / 256; k++) {
            int i = t + k * 256;
            if (i < nvalid) {
                int s = src[base + i];
                int d = dst[base + i];
                unsigned int p = ((unsigned int)d << 16) | (unsigned int)s;
                mypack[k] = p;
                atomicAdd(&hist[d >> 6], 1);
            }
        }
        __syncthreads();
        for (int i = t; i < NBUCK; i += 256) {
            int h = hist[i];
            delta[i] = (h > 0) ? atomicAdd(&bucket_cnt[i], h) : 0;
        }
        __syncthreads();
        scan_nbuck_excl(hist, part);            // hist -> local exclusive offsets
        for (int i = t; i < NBUCK; i += 256) delta[i] -= hist[i];
        __syncthreads();
#pragma unroll
        for (int k = 0; k < CHUNK / 256; k++) {
            int i = t + k * 256;
            if (i < nvalid) {
                unsigned int p = mypack[k];
                int slot = atomicAdd(&hist[p >> 22], 1);
                stage[slot] = p;
            }
        }
        __syncthreads();
        for (int i = t; i < nvalid; i += 256) {
            unsigned int p = stage[i];
            int b = p >> 22;
            int pos = delta[b] + i;
            if (pos < BCAP) region[(size_t)b * BCAP + pos] = p;
            else { int o = atomicAdd(ovf_cnt, 1); ovf[o] = p; }
        }
    }
}

// ---------------- fused place+aggregate: block == one 64-node bucket ------------
// Placement needs NO global prefix when fused: edges go region -> LDS sstage,
// node offsets are a local 64-scan, and the R2-proven gather pipeline reads
// indices from LDS. Deletes: k_place launch, global esrc/offs roundtrip
// (~10 MB), the per-block 784-wide scan; placement of block B overlaps
// aggregation of block A. Aggregate inner loop is R2's verbatim: 2x16-deep
// A/B staging, readlane scalar addressing, sentinel masking (a1[N]=-inf,
// ftb[N]=0), v_exp_f32 on log2e-prescaled logits.
__device__ __forceinline__ void consume16(const float* a1v, const unsigned int* p,
                                          float a2h, float& l, float& accx, float& accy) {
#pragma unroll
    for (int k = 0; k < 16; k++) {
        float t = a1v[k] + a2h;
        float u = fmaxf(t, 0.2f * t);              // leaky (log2-scaled)
        float e;
        asm("v_exp_f32 %0, %1" : "=v"(e) : "v"(u)); // 2^u == exp(orig)
        l += e;
        accx = fmaf(e, __uint_as_float(p[k] << 16), accx);
        accy = fmaf(e, __uint_as_float(p[k] & 0xffff0000u), accy);
    }
}

template <int GB>
__device__ __forceinline__ void issue16(int sv, const float* __restrict__ a1,
                                        const unsigned short* __restrict__ ftb,
                                        int hl, int dimoff,
                                        float* a1v, unsigned int* p) {
#pragma unroll
    for (int k = 0; k < 16; k++) {
        int s = __builtin_amdgcn_readlane(sv, GB + k);   // SGPR -> scalar addressing
        a1v[k] = a1[(size_t)s * N_HEADS + hl];
        p[k]   = *(const unsigned int*)(ftb + (size_t)s * HD + dimoff);
    }
}

__global__ __launch_bounds__(256, 4) void k_place_agg(
    const unsigned short* __restrict__ ftb, const float* __restrict__ a1,
    const float* __restrict__ a2, const unsigned int* __restrict__ region,
    const int* __restrict__ bucket_cnt, const int* __restrict__ ovf_cnt,
    const unsigned int* __restrict__ ovf, float* __restrict__ out) {
    int b = blockIdx.x;
    int t = threadIdx.x;

    __shared__ int hist[64], sc[64], curs[64], loff[65];
    __shared__ unsigned short sstage[BCAP + 64];   // +64: masked over-read pad

    int truec = bucket_cnt[b];
    int rc = min(truec, BCAP);
    const unsigned int* reg = region + (size_t)b * BCAP;

    if (t < 64) hist[t] = 0;
    __syncthreads();
    for (int i = t; i < rc; i += 256) atomicAdd(&hist[(reg[i] >> 16) & 63], 1);
    __syncthreads();
    int h = (t < 64) ? hist[t] : 0;
    if (t < 64) sc[t] = h;
    __syncthreads();
    for (int d = 1; d < 64; d <<= 1) {
        int u = (t >= d && t < 64) ? sc[t - d] : 0;
        __syncthreads();
        if (t < 64) sc[t] += u;
        __syncthreads();
    }
    if (t < 64) { loff[t] = sc[t] - h; curs[t] = sc[t] - h; }
    if (t == 63) loff[64] = sc[63];
    __syncthreads();
    for (int i = t; i < rc; i += 256) {
        unsigned int p = reg[i];
        int pos = atomicAdd(&curs[(p >> 16) & 63], 1);
        sstage[pos] = (unsigned short)(p & 0xffffu);
    }
    __syncthreads();

    // ---------------- aggregation: 4 waves x 16 nodes each ----------------
    int wid  = t >> 6;
    int lane = t & 63;
    int hl = lane >> 3;                       // head for this lane's dim pair
    int dimoff = lane * 2;
    int no = __builtin_amdgcn_readfirstlane(*ovf_cnt);   // ~always 0

    for (int ni = 0; ni < 16; ni++) {
        int nl = wid * 16 + ni;
        int node = b * 64 + nl;
        if (node >= N_NODES) break;
        int st = __builtin_amdgcn_readfirstlane(loff[nl]);
        int en = __builtin_amdgcn_readfirstlane(loff[nl + 1]);
        float a2h = a2[(size_t)node * N_HEADS + hl];
        float accx = 0.f, accy = 0.f, l = 0.f;

        for (int done = st; done < en; done += 64) {
            int nbc = en - done; if (nbc > 64) nbc = 64;
            int v = (int)sstage[done + lane];       // LDS; pad covers tail lanes
            int sv = (lane < nbc) ? v : N_NODES;    // sentinel for lanes past end

            float a1A[16], a1B[16];
            unsigned int pA[16], pB[16];
            issue16<0>(sv, a1, ftb, hl, dimoff, a1A, pA);
            if (nbc > 16) issue16<16>(sv, a1, ftb, hl, dimoff, a1B, pB);
            consume16(a1A, pA, a2h, l, accx, accy);
            if (nbc > 32) issue16<32>(sv, a1, ftb, hl, dimoff, a1A, pA);
            if (nbc > 16) consume16(a1B, pB, a2h, l, accx, accy);
            if (nbc > 48) issue16<48>(sv, a1, ftb, hl, dimoff, a1B, pB);
            if (nbc > 32) consume16(a1A, pA, a2h, l, accx, accy);
            if (nbc > 48) consume16(a1B, pB, a2h, l, accx, accy);
        }

        if (no > 0) {                         // statistically never; correctness path
            for (int i = 0; i < no; i++) {
                unsigned int pk = ovf[i];
                if ((int)(pk >> 16) == node) {
                    int s = (int)(pk & 0xffffu);
                    float a1v = a1[(size_t)s * N_HEADS + hl];
                    unsigned int p = *(const unsigned int*)(ftb + (size_t)s * HD + dimoff);
                    float tt = a1v + a2h;
                    float uu = fmaxf(tt, 0.2f * tt);
                    float ee;
                    asm("v_exp_f32 %0, %1" : "=v"(ee) : "v"(uu));
                    l += ee;
                    accx = fmaf(ee, __uint_as_float(p << 16), accx);
                    accy = fmaf(ee, __uint_as_float(p & 0xffff0000u), accy);
                }
            }
        }

        float invl = (l > 0.f) ? 1.f / l : 0.f;
        float2 o; o.x = accx * invl; o.y = accy * invl;
        *(float2*)(out + (size_t)node * HD + dimoff) = o;
    }
}

// ---------------- host launcher ----------------
extern "C" void kernel_launch(void* const* d_in, const int* in_sizes, int n_in,
                              void* d_out, int out_size, void* d_ws, size_t ws_size,
                              hipStream_t stream) {
    const float* x      = (const float*)d_in[0];
    const float* W      = (const float*)d_in[1];
    const float* attn_l = (const float*)d_in[2];
    const float* attn_r = (const float*)d_in[3];
    const int*   src    = (const int*)d_in[4];
    const int*   dst    = (const int*)d_in[5];
    float* out = (float*)d_out;

    char* ws = (char*)d_ws;
    size_t o = 0;
    auto alloc = [&](size_t bytes) -> char* {
        char* p = ws + o;
        o = (o + bytes + 255) & ~(size_t)255;
        return p;
    };
    // +1 sentinel row on ftb (zeros) and a1 (-inf)
    unsigned short* ftb  = (unsigned short*)alloc((size_t)(N_NODES + 1) * HD * 2);
    float* a1            = (float*)alloc((size_t)(N_NODES + 1) * N_HEADS * 4);
    float* a2            = (float*)alloc((size_t)N_NODES * N_HEADS * 4);
    unsigned short* Wb   = (unsigned short*)alloc((size_t)HD * IN_DIM * 2);    // 32 KB
    unsigned int* region = (unsigned int*)alloc((size_t)NBUCK * BCAP * 4);     // 8.0 MB
    int* bucket_cnt      = (int*)alloc((size_t)NBUCK * 4);
    int* ovf_cnt         = (int*)alloc(4);
    unsigned int* ovf    = (unsigned int*)alloc((size_t)N_EDGES * 4);          // 6.4 MB

    (void)in_sizes; (void)n_in; (void)out_size; (void)ws_size;

    k_prep<<<16, 256, 0, stream>>>(W, Wb, bucket_cnt, ovf_cnt, ftb, a1);
    k_proj_bin<<<PBLK + BIN_BLOCKS, 256, 0, stream>>>(
        x, Wb, attn_l, attn_r, ftb, a1, a2,
        src, dst, region, bucket_cnt, ovf_cnt, ovf);
    k_place_agg<<<NBUCK, 256, 0, stream>>>(ftb, a1, a2, region, bucket_cnt,
                                           ovf_cnt, ovf, out);
}

// Round 9
// 205.469 us; speedup vs baseline: 2.6002x; 1.0300x over previous
//
#include <hip/hip_runtime.h>
#include <math.h>

#define N_NODES 50000
#define N_EDGES 1600000
#define IN_DIM 128
#define N_HEADS 8
#define OUT_DIM 16
#define HD 128            // N_HEADS * OUT_DIM
#define NBUCK 784         // dst>>6: 64 nodes per bucket
#define BCAP 2560         // region capacity per bucket (avg ~2041)
#define CHUNK 4096        // edges per bin block
#define BIN_BLOCKS ((N_EDGES + CHUNK - 1) / CHUNK)   // 391
#define NTILE 3125        // 50000/16 M-tiles (exact)
#define PBLK ((NTILE + 3) / 4)                        // 782 proj blocks (4 waves each)
#define TROW 132          // LDS tile row stride in floats (128 + 4 pad)
#define LOG2E 1.4426950408889634f

typedef __attribute__((ext_vector_type(8))) short bf16x8;
typedef __attribute__((ext_vector_type(4))) float f32x4;

__device__ __forceinline__ unsigned short f2bf(float f) {
    union { float f; unsigned int u; } v; v.f = f;
    unsigned int u = v.u;
    unsigned int r = (u + 0x7fffu + ((u >> 16) & 1u)) >> 16;   // RN-even
    return (unsigned short)r;
}

// exclusive scan of arr[0..NBUCK) in place; part[256] scratch; all 256 threads.
__device__ __forceinline__ void scan_nbuck_excl(int* arr, int* part) {
    int t = threadIdx.x;
    int v0 = 0, v1 = 0, v2 = 0, v3 = 0, cs = 0;
    if (t < NBUCK / 4) {
        v0 = arr[4 * t]; v1 = arr[4 * t + 1]; v2 = arr[4 * t + 2]; v3 = arr[4 * t + 3];
        cs = v0 + v1 + v2 + v3;
    }
    part[t] = cs;
    __syncthreads();
    for (int d = 1; d < 256; d <<= 1) {
        int u = (t >= d) ? part[t - d] : 0;
        __syncthreads();
        part[t] += u;
        __syncthreads();
    }
    if (t < NBUCK / 4) {
        int run = part[t] - cs;
        arr[4 * t] = run; run += v0;
        arr[4 * t + 1] = run; run += v1;
        arr[4 * t + 2] = run; run += v2;
        arr[4 * t + 3] = run;
    }
    __syncthreads();
}

// ---------------- fused: MFMA projection (blocks < PBLK) | edge binning ----------
// k_prep is gone: W is read as f32 and converted to bf16 in-register at
// fragment-build time (identical f2bf -> bit-identical Wb values); counters are
// zeroed by a hipMemsetAsync; sentinel rows (ftb[N]=0, a1[N]=-inf for free edge
// masking in aggregate) are written by proj block 0 (aggregate launches later).
__global__ __launch_bounds__(256) void k_proj_bin(
    const float* __restrict__ x, const float* __restrict__ W,
    const float* __restrict__ attn_l, const float* __restrict__ attn_r,
    unsigned short* __restrict__ ftb, float* __restrict__ a1, float* __restrict__ a2,
    const int* __restrict__ src, const int* __restrict__ dst,
    unsigned int* __restrict__ region, int* __restrict__ bucket_cnt,
    int* __restrict__ ovf_cnt, unsigned int* __restrict__ ovf) {
    // union: proj 4 wave-private f32 tiles 16x132 (33792 B) | bin 23680 B
    __shared__ __align__(16) char smem[4 * 16 * TROW * 4];
    int tid = threadIdx.x;

    if (blockIdx.x < PBLK) {
        // ---------------- MFMA projection branch ----------------
        if (blockIdx.x == 0 && tid < 64) {   // sentinel rows for aggregate
            ((unsigned int*)(ftb + (size_t)N_NODES * HD))[tid] = 0u;
            if (tid < N_HEADS)
                a1[(size_t)N_NODES * N_HEADS + tid] = __int_as_float(0xff800000);
        }
        int wid  = tid >> 6;
        int tile = blockIdx.x * 4 + wid;
        if (tile >= NTILE) return;           // no barriers in this branch
        int lane = tid & 63;
        int m = lane & 15, q = lane >> 4;
        int node0 = tile * 16;

        // A fragments: x[node0+m][ks*32 + q*8 .. +7], fp32 -> bf16
        const float* xr = x + (size_t)(node0 + m) * IN_DIM + q * 8;
        float4 xa[4][2];
#pragma unroll
        for (int ks = 0; ks < 4; ks++) {
            xa[ks][0] = *(const float4*)(xr + ks * 32);
            xa[ks][1] = *(const float4*)(xr + ks * 32 + 4);
        }
        bf16x8 afr[4];
#pragma unroll
        for (int ks = 0; ks < 4; ks++) {
            afr[ks][0] = (short)f2bf(xa[ks][0].x); afr[ks][1] = (short)f2bf(xa[ks][0].y);
            afr[ks][2] = (short)f2bf(xa[ks][0].z); afr[ks][3] = (short)f2bf(xa[ks][0].w);
            afr[ks][4] = (short)f2bf(xa[ks][1].x); afr[ks][5] = (short)f2bf(xa[ks][1].y);
            afr[ks][6] = (short)f2bf(xa[ks][1].z); afr[ks][7] = (short)f2bf(xa[ks][1].w);
        }

        float* tl = (float*)smem + wid * (16 * TROW);

        // heads loop: B frag = W[h*16+m][ks*32 + q*8 .. +7], f32 -> bf16 in-register
#pragma unroll
        for (int h = 0; h < N_HEADS; h++) {
            const float* wrow = W + (size_t)(h * 16 + m) * IN_DIM + q * 8;
            f32x4 c = {0.f, 0.f, 0.f, 0.f};
#pragma unroll
            for (int ks = 0; ks < 4; ks++) {
                float4 w0 = *(const float4*)(wrow + ks * 32);
                float4 w1 = *(const float4*)(wrow + ks * 32 + 4);
                bf16x8 bfr;
                bfr[0] = (short)f2bf(w0.x); bfr[1] = (short)f2bf(w0.y);
                bfr[2] = (short)f2bf(w0.z); bfr[3] = (short)f2bf(w0.w);
                bfr[4] = (short)f2bf(w1.x); bfr[5] = (short)f2bf(w1.y);
                bfr[6] = (short)f2bf(w1.z); bfr[7] = (short)f2bf(w1.w);
                c = __builtin_amdgcn_mfma_f32_16x16x32_bf16(afr[ks], bfr, c, 0, 0, 0);
            }
            // C layout: col = lane&15, row = q*4 + reg  -> stash in LDS tile
#pragma unroll
            for (int r = 0; r < 4; r++)
                tl[(q * 4 + r) * TROW + h * 16 + m] = c[r];
        }

        // a1/a2: lane -> node (lane&15), heads {lane>>4, (lane>>4)+4}
        // NOTE: pre-scaled by log2(e) so aggregate can use raw v_exp_f32 (2^x).
        int nd = lane & 15;
#pragma unroll
        for (int hi = 0; hi < 2; hi++) {
            int hh = (lane >> 4) + hi * 4;
            const float4* rowv = (const float4*)(tl + nd * TROW + hh * 16);
            const float4* alv  = (const float4*)(attn_l + hh * OUT_DIM);
            const float4* arv  = (const float4*)(attn_r + hh * OUT_DIM);
            float sl = 0.f, sr = 0.f;
#pragma unroll
            for (int d4 = 0; d4 < 4; d4++) {
                float4 fv = rowv[d4];
                float4 al = alv[d4];
                float4 ar = arv[d4];
                sl += fv.x * al.x + fv.y * al.y + fv.z * al.z + fv.w * al.w;
                sr += fv.x * ar.x + fv.y * ar.y + fv.z * ar.z + fv.w * ar.w;
            }
            a1[(node0 + nd) * N_HEADS + hh] = sl * LOG2E;
            a2[(node0 + nd) * N_HEADS + hh] = sr * LOG2E;
        }

        // ft store: pass p covers rows p*4+q; lane m covers 8 cols
#pragma unroll
        for (int p = 0; p < 4; p++) {
            int r = p * 4 + q;
            const float* srcp = tl + r * TROW + m * 8;
            float4 f0 = *(const float4*)(srcp);
            float4 f1 = *(const float4*)(srcp + 4);
            ushort4 u0, u1;
            u0.x = f2bf(f0.x); u0.y = f2bf(f0.y); u0.z = f2bf(f0.z); u0.w = f2bf(f0.w);
            u1.x = f2bf(f1.x); u1.y = f2bf(f1.y); u1.z = f2bf(f1.z); u1.w = f2bf(f1.w);
            ushort4* dstp = (ushort4*)(ftb + (size_t)(node0 + r) * HD + m * 8);
            dstp[0] = u0;
            dstp[1] = u1;
        }
    } else {
        // ---------------- binning branch ----------------
        unsigned int* stage = (unsigned int*)smem;          // 16 KB
        int* hist  = (int*)(smem + 16384);                  // NBUCK
        int* delta = (int*)(smem + 19520);                  // NBUCK
        int* part  = (int*)(smem + 22656);                  // 256

        int t = tid;
        int base = (blockIdx.x - PBLK) * CHUNK;
        int nvalid = min(CHUNK, N_EDGES - base);

        for (int i = t; i < NBUCK; i += 256) hist[i] = 0;
        __syncthreads();

        unsigned int mypack[CHUNK / 256];
#pragma unroll
        for (int k = 0; k < CHUNK / 256; k++) {
            int i = t + k * 256;
            if (i < nvalid) {
                int s = src[base + i];
                int d = dst[base + i];
                unsigned int p = ((unsigned int)d << 16) | (unsigned int)s;
                mypack[k] = p;
                atomicAdd(&hist[d >> 6], 1);
            }
        }
        __syncthreads();
        for (int i = t; i < NBUCK; i += 256) {
            int h = hist[i];
            delta[i] = (h > 0) ? atomicAdd(&bucket_cnt[i], h) : 0;
        }
        __syncthreads();
        scan_nbuck_excl(hist, part);            // hist -> local exclusive offsets
        for (int i = t; i < NBUCK; i += 256) delta[i] -= hist[i];
        __syncthreads();
#pragma unroll
        for (int k = 0; k < CHUNK / 256; k++) {
            int i = t + k * 256;
            if (i < nvalid) {
                unsigned int p = mypack[k];
                int slot = atomicAdd(&hist[p >> 22], 1);
                stage[slot] = p;
            }
        }
        __syncthreads();
        for (int i = t; i < nvalid; i += 256) {
            unsigned int p = stage[i];
            int b = p >> 22;
            int pos = delta[b] + i;
            if (pos < BCAP) region[(size_t)b * BCAP + pos] = p;
            else { int o = atomicAdd(ovf_cnt, 1); ovf[o] = p; }
        }
    }
}

// ---------------- per-bucket CSR offsets + placement (784-way parallel) ----------
// esrc writes for a bucket land in the contiguous range [base_b, base_b+truec)
// (~4 KB). Stage that slice in LDS so the global writes go out coalesced
// instead of 1.6M scattered 2-byte stores.
__global__ __launch_bounds__(256) void k_place(
    const unsigned int* __restrict__ region, const int* __restrict__ bucket_cnt,
    const int* __restrict__ ovf_cnt, const unsigned int* __restrict__ ovf,
    int* __restrict__ offs, unsigned short* __restrict__ esrc) {
    int b = blockIdx.x;
    int t = threadIdx.x;
    __shared__ int sb[NBUCK], part[256];
    __shared__ int hist[64], sc[64], curs[64];
    __shared__ unsigned short sstage[BCAP];

    for (int i = t; i < NBUCK; i += 256) sb[i] = bucket_cnt[i];
    if (t < 64) hist[t] = 0;
    __syncthreads();
    scan_nbuck_excl(sb, part);            // sb -> exclusive bucket prefix

    int truec = bucket_cnt[b];
    int base_b = sb[b];
    int rc = min(truec, BCAP);
    bool fits = (truec <= BCAP);          // statistically always true
    const unsigned int* reg = region + (size_t)b * BCAP;

    for (int i = t; i < rc; i += 256) atomicAdd(&hist[(reg[i] >> 16) & 63], 1);
    int no = 0;
    if (truec > BCAP) {                   // statistically never; correctness fallback
        no = *ovf_cnt;
        for (int i = t; i < no; i += 256)
            if ((int)(ovf[i] >> 22) == b) atomicAdd(&hist[(ovf[i] >> 16) & 63], 1);
    }
    __syncthreads();
    int h = (t < 64) ? hist[t] : 0;
    if (t < 64) sc[t] = h;
    __syncthreads();
    for (int d = 1; d < 64; d <<= 1) {
        int u = (t >= d && t < 64) ? sc[t - d] : 0;
        __syncthreads();
        if (t < 64) sc[t] += u;
        __syncthreads();
    }
    if (t < 64) {
        int pos0 = base_b + sc[t] - h;
        int node = b * 64 + t;
        if (node < N_NODES) offs[node] = pos0;
        curs[t] = pos0;
    }
    if (b == 0 && t == 0) offs[N_NODES] = N_EDGES;
    __syncthreads();
    for (int i = t; i < rc; i += 256) {
        unsigned int p = reg[i];
        int pos = atomicAdd(&curs[(p >> 16) & 63], 1);
        if (fits) sstage[pos - base_b] = (unsigned short)(p & 0xffffu);
        else      esrc[pos] = (unsigned short)(p & 0xffffu);
    }
    if (truec > BCAP) {
        for (int i = t; i < no; i += 256) {
            unsigned int p = ovf[i];
            if ((int)(p >> 22) == b) {
                int pos = atomicAdd(&curs[(p >> 16) & 63], 1);
                esrc[pos] = (unsigned short)(p & 0xffffu);
            }
        }
    }
    __syncthreads();
    if (fits) {
        for (int i = t; i < truec; i += 256)
            esrc[base_b + i] = sstage[i];    // coalesced copy-out
    }
}

// ---------------- aggregation (R2-proven): one-shot index load + A/B pipeline ---
// Per node (avg deg 32, P(deg>64)~0): ONE 64-lane esrc load captures every edge
// index -> single readlane round. Gathers issued in 16-edge groups, 2-deep
// double-buffered (A/B reg staging). Lanes past deg get the SENTINEL node
// (a1 = -inf => e = 0, ftb row = 0) -- free masking, no tail path. off/deg
// forced to SGPRs so all loop control is SALU. Measured roofline for this
// layout: 228 MB post-L2 refill @ ~3.3 TB/s (phase-blocked byte-reduction
// variants all lose more rate than they save in bytes -- R5/R6/R7).
__device__ __forceinline__ void consume16(const float* a1v, const unsigned int* p,
                                          float a2h, float& l, float& accx, float& accy) {
#pragma unroll
    for (int k = 0; k < 16; k++) {
        float t = a1v[k] + a2h;
        float u = fmaxf(t, 0.2f * t);              // leaky (log2-scaled)
        float e;
        asm("v_exp_f32 %0, %1" : "=v"(e) : "v"(u)); // 2^u == exp(orig)
        l += e;
        accx = fmaf(e, __uint_as_float(p[k] << 16), accx);
        accy = fmaf(e, __uint_as_float(p[k] & 0xffff0000u), accy);
    }
}

template <int GB>
__device__ __forceinline__ void issue16(int sv, const float* __restrict__ a1,
                                        const unsigned short* __restrict__ ftb,
                                        int hl, int dimoff,
                                        float* a1v, unsigned int* p) {
#pragma unroll
    for (int k = 0; k < 16; k++) {
        int s = __builtin_amdgcn_readlane(sv, GB + k);   // SGPR -> scalar addressing
        a1v[k] = a1[(size_t)s * N_HEADS + hl];
        p[k]   = *(const unsigned int*)(ftb + (size_t)s * HD + dimoff);
    }
}

__global__ __launch_bounds__(256, 4) void k_aggregate(
    const unsigned short* __restrict__ ftb, const float* __restrict__ a1,
    const float* __restrict__ a2, const int* __restrict__ offs,
    const unsigned short* __restrict__ esrc, float* __restrict__ out) {
    int wid  = threadIdx.x >> 6;
    int lane = threadIdx.x & 63;
    int node = blockIdx.x * 4 + wid;

    int off = __builtin_amdgcn_readfirstlane(offs[node]);
    int deg = __builtin_amdgcn_readfirstlane(offs[node + 1]) - off;
    int hl = lane >> 3;                       // head for this lane's dim pair
    float a2h = a2[node * N_HEADS + hl];
    int dimoff = lane * 2;

    const unsigned short* ep = esrc + off;
    float accx = 0.f, accy = 0.f, l = 0.f;

    int done = 0;
    while (done < deg) {
        int nb = deg - done;
        if (nb > 64) nb = 64;
        // one coalesced load of up to 64 edge indices; lanes >= nb -> sentinel
        int v = (int)ep[done + lane];          // within-workspace over-read, discarded
        int sv = (lane < nb) ? v : N_NODES;

        float a1A[16], a1B[16];
        unsigned int pA[16], pB[16];
        issue16<0>(sv, a1, ftb, hl, dimoff, a1A, pA);
        if (nb > 16) issue16<16>(sv, a1, ftb, hl, dimoff, a1B, pB);
        consume16(a1A, pA, a2h, l, accx, accy);
        if (nb > 32) issue16<32>(sv, a1, ftb, hl, dimoff, a1A, pA);
        if (nb > 16) consume16(a1B, pB, a2h, l, accx, accy);
        if (nb > 48) issue16<48>(sv, a1, ftb, hl, dimoff, a1B, pB);
        if (nb > 32) consume16(a1A, pA, a2h, l, accx, accy);
        if (nb > 48) consume16(a1B, pB, a2h, l, accx, accy);
        done += 64;
    }

    float invl = (deg > 0) ? 1.f / l : 0.f;
    float2 o; o.x = accx * invl; o.y = accy * invl;
    *(float2*)(out + (size_t)node * HD + dimoff) = o;
}

// ---------------- host launcher ----------------
extern "C" void kernel_launch(void* const* d_in, const int* in_sizes, int n_in,
                              void* d_out, int out_size, void* d_ws, size_t ws_size,
                              hipStream_t stream) {
    const float* x      = (const float*)d_in[0];
    const float* W      = (const float*)d_in[1];
    const float* attn_l = (const float*)d_in[2];
    const float* attn_r = (const float*)d_in[3];
    const int*   src    = (const int*)d_in[4];
    const int*   dst    = (const int*)d_in[5];
    float* out = (float*)d_out;

    char* ws = (char*)d_ws;
    size_t o = 0;
    auto alloc = [&](size_t bytes) -> char* {
        char* p = ws + o;
        o = (o + bytes + 255) & ~(size_t)255;
        return p;
    };
    // +1 sentinel row on ftb (zeros) and a1 (-inf), written by proj block 0
    unsigned short* ftb  = (unsigned short*)alloc((size_t)(N_NODES + 1) * HD * 2);
    float* a1            = (float*)alloc((size_t)(N_NODES + 1) * N_HEADS * 4);
    float* a2            = (float*)alloc((size_t)N_NODES * N_HEADS * 4);
    unsigned int* region = (unsigned int*)alloc((size_t)NBUCK * BCAP * 4);     // 8.0 MB
    int* cnt_all         = (int*)alloc((size_t)(NBUCK + 1) * 4);   // bucket_cnt + ovf_cnt
    unsigned int* ovf    = (unsigned int*)alloc((size_t)N_EDGES * 4);          // 6.4 MB
    int* offs            = (int*)alloc((size_t)(N_NODES + 1) * 4);
    unsigned short* esrc = (unsigned short*)alloc((size_t)N_EDGES * 2 + 256);  // +pad for over-read
    int* bucket_cnt = cnt_all;
    int* ovf_cnt    = cnt_all + NBUCK;

    (void)in_sizes; (void)n_in; (void)out_size; (void)ws_size;

    hipMemsetAsync(cnt_all, 0, (size_t)(NBUCK + 1) * 4, stream);
    k_proj_bin<<<PBLK + BIN_BLOCKS, 256, 0, stream>>>(
        x, W, attn_l, attn_r, ftb, a1, a2,
        src, dst, region, bucket_cnt, ovf_cnt, ovf);
    k_place<<<NBUCK, 256, 0, stream>>>(region, bucket_cnt, ovf_cnt, ovf, offs, esrc);
    k_aggregate<<<N_NODES / 4, 256, 0, stream>>>(ftb, a1, a2, offs, esrc, out);
}

// Round 10
// 194.350 us; speedup vs baseline: 2.7490x; 1.0572x over previous
//
#include <hip/hip_runtime.h>
#include <math.h>

#define N_NODES 50000
#define N_EDGES 1600000
#define IN_DIM 128
#define N_HEADS 8
#define OUT_DIM 16
#define HD 128            // N_HEADS * OUT_DIM
#define NBUCK 784         // dst>>6: 64 nodes per bucket
#define BCAP 2560         // region capacity per bucket (avg ~2041)
#define CHUNK 4096        // edges per bin block
#define BIN_BLOCKS ((N_EDGES + CHUNK - 1) / CHUNK)   // 391
#define NTILE 3125        // 50000/16 M-tiles (exact)
#define PBLK ((NTILE + 3) / 4)                        // 782 proj blocks (4 waves each)
#define TROW 132          // LDS tile row stride in floats (128 + 4 pad)
#define LOG2E 1.4426950408889634f

typedef __attribute__((ext_vector_type(8))) short bf16x8;
typedef __attribute__((ext_vector_type(4))) float f32x4;

__device__ __forceinline__ unsigned short f2bf(float f) {
    union { float f; unsigned int u; } v; v.f = f;
    unsigned int u = v.u;
    unsigned int r = (u + 0x7fffu + ((u >> 16) & 1u)) >> 16;   // RN-even
    return (unsigned short)r;
}

// exclusive scan of arr[0..NBUCK) in place; part[256] scratch; all 256 threads.
__device__ __forceinline__ void scan_nbuck_excl(int* arr, int* part) {
    int t = threadIdx.x;
    int v0 = 0, v1 = 0, v2 = 0, v3 = 0, cs = 0;
    if (t < NBUCK / 4) {
        v0 = arr[4 * t]; v1 = arr[4 * t + 1]; v2 = arr[4 * t + 2]; v3 = arr[4 * t + 3];
        cs = v0 + v1 + v2 + v3;
    }
    part[t] = cs;
    __syncthreads();
    for (int d = 1; d < 256; d <<= 1) {
        int u = (t >= d) ? part[t - d] : 0;
        __syncthreads();
        part[t] += u;
        __syncthreads();
    }
    if (t < NBUCK / 4) {
        int run = part[t] - cs;
        arr[4 * t] = run; run += v0;
        arr[4 * t + 1] = run; run += v1;
        arr[4 * t + 2] = run; run += v2;
        arr[4 * t + 3] = run;
    }
    __syncthreads();
}

// ---------------- prep: W(f32) -> Wb(bf16) + zero counters + sentinel rows ----
// Sentinel node N_NODES: a1 row = -inf (exp2 -> 0 => free edge masking in
// aggregate), ftb row = 0 (so e=0 times finite 0 => no NaN).
__global__ void k_prep(const float* __restrict__ W, unsigned short* __restrict__ Wb,
                       int* __restrict__ bucket_cnt, int* __restrict__ ovf_cnt,
                       unsigned short* __restrict__ ftb, float* __restrict__ a1) {
    int g = blockIdx.x * 256 + threadIdx.x;   // 4096 threads over 4096 float4s
    if (g < NBUCK) bucket_cnt[g] = 0;
    if (g == 0) *ovf_cnt = 0;
    if (g < 64) ((unsigned int*)(ftb + (size_t)N_NODES * HD))[g] = 0u;
    if (g >= 64 && g < 64 + N_HEADS)
        a1[(size_t)N_NODES * N_HEADS + (g - 64)] = __int_as_float(0xff800000); // -inf
    if (g >= (HD * IN_DIM) / 4) return;
    float4 v = ((const float4*)W)[g];
    ushort4 us;
    us.x = f2bf(v.x); us.y = f2bf(v.y); us.z = f2bf(v.z); us.w = f2bf(v.w);
    ((ushort4*)Wb)[g] = us;
}

// ---------------- fused: MFMA projection (blocks < PBLK) | edge binning ----------
__global__ __launch_bounds__(256) void k_proj_bin(
    const float* __restrict__ x, const unsigned short* __restrict__ Wb,
    const float* __restrict__ attn_l, const float* __restrict__ attn_r,
    unsigned short* __restrict__ ftb, float* __restrict__ a1, float* __restrict__ a2,
    const int* __restrict__ src, const int* __restrict__ dst,
    unsigned int* __restrict__ region, int* __restrict__ bucket_cnt,
    int* __restrict__ ovf_cnt, unsigned int* __restrict__ ovf) {
    // union: proj 4 wave-private f32 tiles 16x132 (33792 B) | bin 23680 B
    __shared__ __align__(16) char smem[4 * 16 * TROW * 4];
    int tid = threadIdx.x;

    if (blockIdx.x < PBLK) {
        // ---------------- MFMA projection branch ----------------
        int wid  = tid >> 6;
        int tile = blockIdx.x * 4 + wid;
        if (tile >= NTILE) return;           // no barriers in this branch
        int lane = tid & 63;
        int m = lane & 15, q = lane >> 4;
        int node0 = tile * 16;

        // A fragments: x[node0+m][ks*32 + q*8 .. +7], fp32 -> bf16
        const float* xr = x + (size_t)(node0 + m) * IN_DIM + q * 8;
        float4 xa[4][2];
#pragma unroll
        for (int ks = 0; ks < 4; ks++) {
            xa[ks][0] = *(const float4*)(xr + ks * 32);
            xa[ks][1] = *(const float4*)(xr + ks * 32 + 4);
        }
        bf16x8 afr[4];
#pragma unroll
        for (int ks = 0; ks < 4; ks++) {
            afr[ks][0] = (short)f2bf(xa[ks][0].x); afr[ks][1] = (short)f2bf(xa[ks][0].y);
            afr[ks][2] = (short)f2bf(xa[ks][0].z); afr[ks][3] = (short)f2bf(xa[ks][0].w);
            afr[ks][4] = (short)f2bf(xa[ks][1].x); afr[ks][5] = (short)f2bf(xa[ks][1].y);
            afr[ks][6] = (short)f2bf(xa[ks][1].z); afr[ks][7] = (short)f2bf(xa[ks][1].w);
        }

        float* tl = (float*)smem + wid * (16 * TROW);

        // heads loop: B frag = Wb[h*16+m][ks*32 + q*8 .. +7] (original W layout!)
#pragma unroll
        for (int h = 0; h < N_HEADS; h++) {
            const unsigned short* wrow = Wb + (size_t)(h * 16 + m) * IN_DIM + q * 8;
            f32x4 c = {0.f, 0.f, 0.f, 0.f};
#pragma unroll
            for (int ks = 0; ks < 4; ks++) {
                bf16x8 bfr = *(const bf16x8*)(wrow + ks * 32);
                c = __builtin_amdgcn_mfma_f32_16x16x32_bf16(afr[ks], bfr, c, 0, 0, 0);
            }
            // C layout: col = lane&15, row = q*4 + reg  -> stash in LDS tile
#pragma unroll
            for (int r = 0; r < 4; r++)
                tl[(q * 4 + r) * TROW + h * 16 + m] = c[r];
        }

        // a1/a2: lane -> node (lane&15), heads {lane>>4, (lane>>4)+4}
        // NOTE: pre-scaled by log2(e) so aggregate can use raw v_exp_f32 (2^x).
        int nd = lane & 15;
#pragma unroll
        for (int hi = 0; hi < 2; hi++) {
            int hh = (lane >> 4) + hi * 4;
            const float4* rowv = (const float4*)(tl + nd * TROW + hh * 16);
            const float4* alv  = (const float4*)(attn_l + hh * OUT_DIM);
            const float4* arv  = (const float4*)(attn_r + hh * OUT_DIM);
            float sl = 0.f, sr = 0.f;
#pragma unroll
            for (int d4 = 0; d4 < 4; d4++) {
                float4 fv = rowv[d4];
                float4 al = alv[d4];
                float4 ar = arv[d4];
                sl += fv.x * al.x + fv.y * al.y + fv.z * al.z + fv.w * al.w;
                sr += fv.x * ar.x + fv.y * ar.y + fv.z * ar.z + fv.w * ar.w;
            }
            a1[(node0 + nd) * N_HEADS + hh] = sl * LOG2E;
            a2[(node0 + nd) * N_HEADS + hh] = sr * LOG2E;
        }

        // ft store: pass p covers rows p*4+q; lane m covers 8 cols
#pragma unroll
        for (int p = 0; p < 4; p++) {
            int r = p * 4 + q;
            const float* srcp = tl + r * TROW + m * 8;
            float4 f0 = *(const float4*)(srcp);
            float4 f1 = *(const float4*)(srcp + 4);
            ushort4 u0, u1;
            u0.x = f2bf(f0.x); u0.y = f2bf(f0.y); u0.z = f2bf(f0.z); u0.w = f2bf(f0.w);
            u1.x = f2bf(f1.x); u1.y = f2bf(f1.y); u1.z = f2bf(f1.z); u1.w = f2bf(f1.w);
            ushort4* dstp = (ushort4*)(ftb + (size_t)(node0 + r) * HD + m * 8);
            dstp[0] = u0;
            dstp[1] = u1;
        }
    } else {
        // ---------------- binning branch ----------------
        unsigned int* stage = (unsigned int*)smem;          // 16 KB
        int* hist  = (int*)(smem + 16384);                  // NBUCK
        int* delta = (int*)(smem + 19520);                  // NBUCK
        int* part  = (int*)(smem + 22656);                  // 256

        int t = tid;
        int base = (blockIdx.x - PBLK) * CHUNK;
        int nvalid = min(CHUNK, N_EDGES - base);

        for (int i = t; i < NBUCK; i += 256) hist[i] = 0;
        __syncthreads();

        unsigned int mypack[CHUNK / 256];
#pragma unroll
        for (int k = 0; k < CHUNK / 256; k++) {
            int i = t + k * 256;
            if (i < nvalid) {
                int s = src[base + i];
                int d = dst[base + i];
                unsigned int p = ((unsigned int)d << 16) | (unsigned int)s;
                mypack[k] = p;
                atomicAdd(&hist[d >> 6], 1);
            }
        }
        __syncthreads();
        for (int i = t; i < NBUCK; i += 256) {
            int h = hist[i];
            delta[i] = (h > 0) ? atomicAdd(&bucket_cnt[i], h) : 0;
        }
        __syncthreads();
        scan_nbuck_excl(hist, part);            // hist -> local exclusive offsets
        for (int i = t; i < NBUCK; i += 256) delta[i] -= hist[i];
        __syncthreads();
#pragma unroll
        for (int k = 0; k < CHUNK / 256; k++) {
            int i = t + k * 256;
            if (i < nvalid) {
                unsigned int p = mypack[k];
                int slot = atomicAdd(&hist[p >> 22], 1);
                stage[slot] = p;
            }
        }
        __syncthreads();
        for (int i = t; i < nvalid; i += 256) {
            unsigned int p = stage[i];
            int b = p >> 22;
            int pos = delta[b] + i;
            if (pos < BCAP) region[(size_t)b * BCAP + pos] = p;
            else { int o = atomicAdd(ovf_cnt, 1); ovf[o] = p; }
        }
    }
}

// ---------------- per-bucket CSR offsets + placement (784-way parallel) ----------
// esrc writes for a bucket land in the contiguous range [base_b, base_b+truec)
// (~4 KB). Stage that slice in LDS so the global writes go out coalesced
// instead of 1.6M scattered 2-byte stores.
__global__ __launch_bounds__(256) void k_place(
    const unsigned int* __restrict__ region, const int* __restrict__ bucket_cnt,
    const int* __restrict__ ovf_cnt, const unsigned int* __restrict__ ovf,
    int* __restrict__ offs, unsigned short* __restrict__ esrc) {
    int b = blockIdx.x;
    int t = threadIdx.x;
    __shared__ int sb[NBUCK], part[256];
    __shared__ int hist[64], sc[64], curs[64];
    __shared__ unsigned short sstage[BCAP];

    for (int i = t; i < NBUCK; i += 256) sb[i] = bucket_cnt[i];
    if (t < 64) hist[t] = 0;
    __syncthreads();
    scan_nbuck_excl(sb, part);            // sb -> exclusive bucket prefix

    int truec = bucket_cnt[b];
    int base_b = sb[b];
    int rc = min(truec, BCAP);
    bool fits = (truec <= BCAP);          // statistically always true
    const unsigned int* reg = region + (size_t)b * BCAP;

    for (int i = t; i < rc; i += 256) atomicAdd(&hist[(reg[i] >> 16) & 63], 1);
    int no = 0;
    if (truec > BCAP) {                   // statistically never; correctness fallback
        no = *ovf_cnt;
        for (int i = t; i < no; i += 256)
            if ((int)(ovf[i] >> 22) == b) atomicAdd(&hist[(ovf[i] >> 16) & 63], 1);
    }
    __syncthreads();
    int h = (t < 64) ? hist[t] : 0;
    if (t < 64) sc[t] = h;
    __syncthreads();
    for (int d = 1; d < 64; d <<= 1) {
        int u = (t >= d && t < 64) ? sc[t - d] : 0;
        __syncthreads();
        if (t < 64) sc[t] += u;
        __syncthreads();
    }
    if (t < 64) {
        int pos0 = base_b + sc[t] - h;
        int node = b * 64 + t;
        if (node < N_NODES) offs[node] = pos0;
        curs[t] = pos0;
    }
    if (b == 0 && t == 0) offs[N_NODES] = N_EDGES;
    __syncthreads();
    for (int i = t; i < rc; i += 256) {
        unsigned int p = reg[i];
        int pos = atomicAdd(&curs[(p >> 16) & 63], 1);
        if (fits) sstage[pos - base_b] = (unsigned short)(p & 0xffffu);
        else      esrc[pos] = (unsigned short)(p & 0xffffu);
    }
    if (truec > BCAP) {
        for (int i = t; i < no; i += 256) {
            unsigned int p = ovf[i];
            if ((int)(p >> 22) == b) {
                int pos = atomicAdd(&curs[(p >> 16) & 63], 1);
                esrc[pos] = (unsigned short)(p & 0xffffu);
            }
        }
    }
    __syncthreads();
    if (fits) {
        for (int i = t; i < truec; i += 256)
            esrc[base_b + i] = sstage[i];    // coalesced copy-out
    }
}

// ---------------- aggregation: one-shot index load + 2-deep gather pipeline ---
// Per node (avg deg 32, P(deg>64)~0): ONE 64-lane esrc load captures every edge
// index -> single readlane round. Gathers issued in 16-edge groups, 2-deep
// double-buffered (A/B reg staging). Lanes past deg get the SENTINEL node
// (a1 = -inf => e = 0, ftb row = 0) -- free masking, no tail path, no per-edge
// guards. off/deg forced to SGPRs so all loop control is SALU.
// Measured structural roofline for this layout: 198 MB post-L2 refill at
// ~3.3 TB/s (phase-blocked byte-reduction variants R5/R6/R7 all lose more
// rate to segment fragmentation than they save in bytes; persistent-wave and
// fused variants R4/R8 raise bytes faster than rate).
__device__ __forceinline__ void consume16(const float* a1v, const unsigned int* p,
                                          float a2h, float& l, float& accx, float& accy) {
#pragma unroll
    for (int k = 0; k < 16; k++) {
        float t = a1v[k] + a2h;
        float u = fmaxf(t, 0.2f * t);              // leaky (log2-scaled)
        float e;
        asm("v_exp_f32 %0, %1" : "=v"(e) : "v"(u)); // 2^u == exp(orig)
        l += e;
        accx = fmaf(e, __uint_as_float(p[k] << 16), accx);
        accy = fmaf(e, __uint_as_float(p[k] & 0xffff0000u), accy);
    }
}

template <int GB>
__device__ __forceinline__ void issue16(int sv, const float* __restrict__ a1,
                                        const unsigned short* __restrict__ ftb,
                                        int hl, int dimoff,
                                        float* a1v, unsigned int* p) {
#pragma unroll
    for (int k = 0; k < 16; k++) {
        int s = __builtin_amdgcn_readlane(sv, GB + k);   // SGPR -> scalar addressing
        a1v[k] = a1[(size_t)s * N_HEADS + hl];
        p[k]   = *(const unsigned int*)(ftb + (size_t)s * HD + dimoff);
    }
}

__global__ __launch_bounds__(256, 4) void k_aggregate(
    const unsigned short* __restrict__ ftb, const float* __restrict__ a1,
    const float* __restrict__ a2, const int* __restrict__ offs,
    const unsigned short* __restrict__ esrc, float* __restrict__ out) {
    int wid  = threadIdx.x >> 6;
    int lane = threadIdx.x & 63;
    int node = blockIdx.x * 4 + wid;

    int off = __builtin_amdgcn_readfirstlane(offs[node]);
    int deg = __builtin_amdgcn_readfirstlane(offs[node + 1]) - off;
    int hl = lane >> 3;                       // head for this lane's dim pair
    float a2h = a2[node * N_HEADS + hl];
    int dimoff = lane * 2;

    const unsigned short* ep = esrc + off;
    float accx = 0.f, accy = 0.f, l = 0.f;

    int done = 0;
    while (done < deg) {
        int nb = deg - done;
        if (nb > 64) nb = 64;
        // one coalesced load of up to 64 edge indices; lanes >= nb -> sentinel
        int v = (int)ep[done + lane];          // within-workspace over-read, discarded
        int sv = (lane < nb) ? v : N_NODES;

        float a1A[16], a1B[16];
        unsigned int pA[16], pB[16];
        issue16<0>(sv, a1, ftb, hl, dimoff, a1A, pA);
        if (nb > 16) issue16<16>(sv, a1, ftb, hl, dimoff, a1B, pB);
        consume16(a1A, pA, a2h, l, accx, accy);
        if (nb > 32) issue16<32>(sv, a1, ftb, hl, dimoff, a1A, pA);
        if (nb > 16) consume16(a1B, pB, a2h, l, accx, accy);
        if (nb > 48) issue16<48>(sv, a1, ftb, hl, dimoff, a1B, pB);
        if (nb > 32) consume16(a1A, pA, a2h, l, accx, accy);
        if (nb > 48) consume16(a1B, pB, a2h, l, accx, accy);
        done += 64;
    }

    float invl = (deg > 0) ? 1.f / l : 0.f;
    float2 o; o.x = accx * invl; o.y = accy * invl;
    *(float2*)(out + (size_t)node * HD + dimoff) = o;
}

// ---------------- host launcher ----------------
extern "C" void kernel_launch(void* const* d_in, const int* in_sizes, int n_in,
                              void* d_out, int out_size, void* d_ws, size_t ws_size,
                              hipStream_t stream) {
    const float* x      = (const float*)d_in[0];
    const float* W      = (const float*)d_in[1];
    const float* attn_l = (const float*)d_in[2];
    const float* attn_r = (const float*)d_in[3];
    const int*   src    = (const int*)d_in[4];
    const int*   dst    = (const int*)d_in[5];
    float* out = (float*)d_out;

    char* ws = (char*)d_ws;
    size_t o = 0;
    auto alloc = [&](size_t bytes) -> char* {
        char* p = ws + o;
        o = (o + bytes + 255) & ~(size_t)255;
        return p;
    };
    // +1 sentinel row on ftb (zeros) and a1 (-inf)
    unsigned short* ftb  = (unsigned short*)alloc((size_t)(N_NODES + 1) * HD * 2);
    float* a1            = (float*)alloc((size_t)(N_NODES + 1) * N_HEADS * 4);
    float* a2            = (float*)alloc((size_t)N_NODES * N_HEADS * 4);
    unsigned short* Wb   = (unsigned short*)alloc((size_t)HD * IN_DIM * 2);    // 32 KB
    unsigned int* region = (unsigned int*)alloc((size_t)NBUCK * BCAP * 4);     // 8.0 MB
    int* bucket_cnt      = (int*)alloc((size_t)NBUCK * 4);
    int* ovf_cnt         = (int*)alloc(4);
    unsigned int* ovf    = (unsigned int*)alloc((size_t)N_EDGES * 4);          // 6.4 MB
    int* offs            = (int*)alloc((size_t)(N_NODES + 1) * 4);
    unsigned short* esrc = (unsigned short*)alloc((size_t)N_EDGES * 2 + 256);  // +pad for over-read

    (void)in_sizes; (void)n_in; (void)out_size; (void)ws_size;

    k_prep<<<16, 256, 0, stream>>>(W, Wb, bucket_cnt, ovf_cnt, ftb, a1);
    k_proj_bin<<<PBLK + BIN_BLOCKS, 256, 0, stream>>>(
        x, Wb, attn_l, attn_r, ftb, a1, a2,
        src, dst, region, bucket_cnt, ovf_cnt, ovf);
    k_place<<<NBUCK, 256, 0, stream>>>(region, bucket_cnt, ovf_cnt, ovf, offs, esrc);
    k_aggregate<<<N_NODES / 4, 256, 0, stream>>>(ftb, a1, a2, offs, esrc, out);
}